// Round 9
// baseline (1576.303 us; speedup 1.0000x reference)
//
#include <hip/hip_runtime.h>

#define NEGV -1e30f
constexpr int Bn = 64, Tn = 2000, Cn = 256, Ln = 128;

__device__ __forceinline__ float wave_max(float v) {
#pragma unroll
  for (int s = 32; s; s >>= 1) v = fmaxf(v, __shfl_xor(v, s, 64));
  return v;
}
__device__ __forceinline__ float wave_sum(float v) {
#pragma unroll
  for (int s = 32; s; s >>= 1) v += __shfl_xor(v, s, 64);
  return v;
}
__device__ __forceinline__ unsigned int bf16_rne(float f) {
  return (__float_as_uint(f) + 0x8000u) >> 16;  // round-half-up bf16
}

// Blocks 0..63: denominator DP (dense bigram FSA), 512 threads = 8 waves.
//   Lane layout (LDS delivered-bytes minimized): wave w owns cols [32w,32w+32).
//   Lane = (g = lane>>3, c = lane&7): dots rows [32g,32g+32) of the 4 cols
//   {32w+c+8k, k=0..3} (64 v_dot2). p-read = 4xb128 = 64 B/lane (32 KB/step
//   vs 128 KB in r6). 8-way i-combine via shfl_xor(8,16,32) in-register.
//   Epilogue on g<4 lanes (one col each). ONE barrier per step.
//   m(t) = beta0(t-2): exact offset (added back), via 2-slot m_lds scalar.
// Blocks 64..127: numerator DP (label chain), 1 wave, shuffle-only.
__global__ __launch_bounds__(512, 1) void lfmmi_main(
    const float* __restrict__ nnet, const float* __restrict__ trans,
    const int* __restrict__ labels, const int* __restrict__ durs,
    float* __restrict__ den_out, float* __restrict__ num_out) {
  __shared__ __align__(16) unsigned short p_bf[2][Cn];  // double-buffered p
  __shared__ __align__(16) float fin[Cn];               // final-LSE scratch
  __shared__ float m_lds[2];                            // beta0 history
  const int tid = threadIdx.x;
  const int blk = blockIdx.x;

  if (blk < Bn) {
    // ---------------- denominator ----------------
    const int b = blk;
    const int dur = durs[b];
    const int w = tid >> 6;      // wave -> col group [32w, 32w+32)
    const int lane = tid & 63;
    const int g = lane >> 3;     // i-group: rows [32g, 32g+32)
    const int c = lane & 7;      // col offset within group
    const int gm = g & 3;
    const int j0 = 32 * w + c + 8 * gm;  // owned col (epilogue, g<4)

    // E rows [32g,32g+32) of cols {32w+c+8k}, packed bf16x2 -> 64 VGPRs
    unsigned int Ep[16][4];
#pragma unroll
    for (int p = 0; p < 16; ++p) {
#pragma unroll
      for (int k = 0; k < 4; ++k) {
        const int i0 = 32 * g + 2 * p;
        const int j = 32 * w + c + 8 * k;
        const unsigned int lo = bf16_rne(__expf(trans[i0 * Cn + j]));
        const unsigned int hi = bf16_rne(__expf(trans[(i0 + 1) * Cn + j]));
        Ep[p][k] = (lo & 0xffffu) | (hi << 16);
      }
    }

    const float* xb = nnet + (size_t)b * Tn * Cn;
    float beta = xb[j0];       // beta(0)[j0]
    const float m0 = xb[0];    // beta0(0)
    float m_add = m0;          // m(t) add-back for current step
    if (g < 4) p_bf[1][j0] = (unsigned short)bf16_rne(__expf(beta - m0));
    if (tid == 0) m_lds[0] = m0;
    float xn1 = xb[Cn + j0];       // x[1][j0]
    float xn2 = xb[2 * Cn + j0];   // x[2][j0]
    __syncthreads();  // p(1), m_lds[0] visible

    for (int t = 1; t < dur; ++t) {
      const int cur = t & 1;
      const float mn = m_lds[(t - 1) & 1];  // beta0(t-1) = m(t+1)

      // p(t) rows [32g,32g+32): 4 x b128 (64 B/lane; 8 addrs/wave, 2-way bank)
      union { uint4 q[4]; unsigned int u[16]; } P;
      const uint4* ps = (const uint4*)&p_bf[cur][32 * g];
      P.q[0] = ps[0]; P.q[1] = ps[1]; P.q[2] = ps[2]; P.q[3] = ps[3];

      float a0 = 0.f, a1 = 0.f, a2 = 0.f, a3 = 0.f;
#pragma unroll
      for (int p = 0; p < 16; ++p) {
        asm("v_dot2_f32_bf16 %0, %1, %2, %0" : "+v"(a0) : "v"(P.u[p]), "v"(Ep[p][0]));
        asm("v_dot2_f32_bf16 %0, %1, %2, %0" : "+v"(a1) : "v"(P.u[p]), "v"(Ep[p][1]));
        asm("v_dot2_f32_bf16 %0, %1, %2, %0" : "+v"(a2) : "v"(P.u[p]), "v"(Ep[p][2]));
        asm("v_dot2_f32_bf16 %0, %1, %2, %0" : "+v"(a3) : "v"(P.u[p]), "v"(Ep[p][3]));
      }
      // 8-way i-combine (rows) across g: in-register butterfly
#pragma unroll
      for (int s = 8; s <= 32; s <<= 1) {
        a0 += __shfl_xor(a0, s, 64);
        a1 += __shfl_xor(a1, s, 64);
        a2 += __shfl_xor(a2, s, 64);
        a3 += __shfl_xor(a3, s, 64);
      }

      if (g < 4) {  // epilogue: one col per lane
        const float sv = (gm & 2) ? ((gm & 1) ? a3 : a2)
                                  : ((gm & 1) ? a1 : a0);
        beta = m_add + __logf(sv) + xn1;  // exact add-back of m(t)
        xn1 = xn2;
        const int tn = (t + 2 < Tn) ? t + 2 : Tn - 1;
        xn2 = xb[(size_t)tn * Cn + j0];   // prefetch depth 2
        // p(t+1) with m(t+1) = beta0(t-1)
        p_bf[cur ^ 1][j0] = (unsigned short)bf16_rne(__expf(beta - mn));
        if (tid == 0) m_lds[t & 1] = beta;  // beta0(t), read at t+1
      }
      m_add = mn;
      __syncthreads();  // the only barrier per step
    }

    // den_score = logsumexp_j(beta)
    if (g < 4) fin[j0] = beta;
    __syncthreads();
    if (tid < 64) {
      const float4 v = ((const float4*)fin)[tid];
      float mx = fmaxf(fmaxf(v.x, v.y), fmaxf(v.z, v.w));
      mx = wave_max(mx);
      float sm = __expf(v.x - mx) + __expf(v.y - mx) +
                 __expf(v.z - mx) + __expf(v.w - mx);
      sm = wave_sum(sm);
      if (tid == 0) den_out[b] = mx + __logf(sm);
    }
  } else {
    // ---------------- numerator: single wave, no barriers ----------------
    const int b = blk - Bn;
    if (tid >= 64) return;
    const int dur = durs[b];
    const int lane = tid;
    const float* xb = nnet + (size_t)b * Tn * Cn;
    const int lab0 = labels[b * Ln + lane];       // label index lane
    const int lab1 = labels[b * Ln + 64 + lane];  // label index lane+64
    float a0 = (lane == 0) ? xb[lab0] : NEGV;
    float a1 = NEGV;
    float ea1 = xb[(size_t)1 * Cn + lab0], eb1 = xb[(size_t)1 * Cn + lab1];
    float ea2 = xb[(size_t)2 * Cn + lab0], eb2 = xb[(size_t)2 * Cn + lab1];
    float ea3 = xb[(size_t)3 * Cn + lab0], eb3 = xb[(size_t)3 * Cn + lab1];
    float ea4 = xb[(size_t)4 * Cn + lab0], eb4 = xb[(size_t)4 * Cn + lab1];

    for (int t = 1; t < dur; ++t) {
      const float ec0 = ea1, ec1 = eb1;
      ea1 = ea2; ea2 = ea3; ea3 = ea4;
      eb1 = eb2; eb2 = eb3; eb3 = eb4;
      const int tn = (t + 4 < Tn) ? t + 4 : Tn - 1;
      ea4 = xb[(size_t)tn * Cn + lab0];
      eb4 = xb[(size_t)tn * Cn + lab1];

      const float p0s = __shfl_up(a0, 1, 64);
      const float p1s = __shfl_up(a1, 1, 64);
      const float w63 = __shfl(a0, 63, 64);  // label 63 -> prev of label 64
      const float prev0 = lane ? p0s : NEGV;
      const float prev1 = lane ? p1s : w63;

      const float mx0 = fmaxf(a0, prev0), d0 = fminf(a0, prev0) - mx0;
      const float mx1 = fmaxf(a1, prev1), d1 = fminf(a1, prev1) - mx1;
      a0 = mx0 + log1pf(__expf(d0)) + ec0;
      a1 = mx1 + log1pf(__expf(d1)) + ec1;
    }
    if (lane == 63) num_out[b] = a1;
  }
}

__global__ void lfmmi_final(const float* __restrict__ den,
                            const float* __restrict__ num,
                            const int* __restrict__ durs,
                            float* __restrict__ out) {
  const int tid = threadIdx.x;  // 64 threads
  float v = num[tid] - den[tid];
  float d = (float)durs[tid];
  v = wave_sum(v);
  d = wave_sum(d);
  if (tid == 0) {
    out[0] = v;
    out[1] = d;
    out[2] = d;
  }
}

extern "C" void kernel_launch(void* const* d_in, const int* in_sizes, int n_in,
                              void* d_out, int out_size, void* d_ws, size_t ws_size,
                              hipStream_t stream) {
  const float* nnet = (const float*)d_in[0];   // (64, 2000, 256) f32
  const float* trans = (const float*)d_in[1];  // (256, 256) f32
  const int* labels = (const int*)d_in[2];     // (64, 128) i32
  const int* durs = (const int*)d_in[3];       // (64,) i32
  float* den_ws = (float*)d_ws;
  float* num_ws = den_ws + Bn;
  lfmmi_main<<<dim3(2 * Bn), dim3(512), 0, stream>>>(nnet, trans, labels, durs,
                                                     den_ws, num_ws);
  lfmmi_final<<<dim3(1), dim3(64), 0, stream>>>(den_ws, num_ws, durs,
                                                (float*)d_out);
}